// Round 1
// baseline (66.055 us; speedup 1.0000x reference)
//
#include <hip/hip_runtime.h>
#include <math.h>

// 4-qubit, depth-10 VQC — exact statevector simulation (16 complex amps),
// one amplitude per lane of a single wave. The reference's ring tensor
// network is exact (no truncation), so statevector evolution is identical.
//
// Amplitude linear index: idx = i0*8 + i1*4 + i2*2 + i3 (qubit n -> mask 8>>n).
// Outputs: |amp[0]|^2, |amp[2]|^2, |amp[15]|^2  (K[0000], K[0010], K[1111]).

#define DEPTH 10
#define NPAR  124   // 4 (psi) + 40 (RX) + 40 (RY) + 40 (RZ)

__global__ __launch_bounds__(64)
void vqc16_kernel(const float* __restrict__ psi,
                  const float* __restrict__ ring,   // [4][2]
                  const float* __restrict__ prx,    // [10][4]
                  const float* __restrict__ pry,
                  const float* __restrict__ prz,
                  float* __restrict__ out)          // [3]
{
    __shared__ float cb[NPAR];
    __shared__ float sb[NPAR];
    const int t = threadIdx.x;

    // Phase 1: all half-angle sincos coefficients in parallel (2 per lane).
    for (int i = t; i < NPAR; i += 64) {
        float th;
        if (i < 4)       th = psi[i];
        else if (i < 44) th = prx[i - 4];
        else if (i < 84) th = pry[i - 44];
        else             th = prz[i - 84];
        float s, c;
        sincosf(0.5f * th, &s, &c);
        cb[i] = c;
        sb[i] = s;
    }
    __syncthreads();

    // Phase 2: statevector evolution, one amplitude per lane.
    // Lanes 16..63 run harmless replicas (xor masks <= 8 keep each
    // 16-lane group closed under the shuffles).
    const int idx = t & 15;
    const int b0 = (idx >> 3) & 1;
    const int b1 = (idx >> 2) & 1;
    const int b2 = (idx >> 1) & 1;
    const int b3 = idx & 1;

    // Initial product state (real): prod_n ring_init[n][bit_n]
    float re = ring[0 + b0] * ring[2 + b1] * ring[4 + b2] * ring[6 + b3];
    float im = 0.0f;

    // RX(th): [[c, -i s], [-i s, c]]
    //   new = c*self - i*s*partner -> re' = c*re + s*p_im ; im' = c*im - s*p_re
    auto RX = [&](int pi, int m) {
        const float c = cb[pi], s = sb[pi];
        const float pre = __shfl_xor(re, m);
        const float pim = __shfl_xor(im, m);
        const float nre = fmaf(c, re,  s * pim);
        const float nim = fmaf(c, im, -s * pre);
        re = nre; im = nim;
    };
    // RY(th): [[c, -s], [s, c]] (real)
    //   bit==0: new = c*self - s*partner ; bit==1: new = c*self + s*partner
    auto RY = [&](int pi, int m) {
        const float c = cb[pi], s = sb[pi];
        const float sg = (idx & m) ? s : -s;
        const float pre = __shfl_xor(re, m);
        const float pim = __shfl_xor(im, m);
        const float nre = fmaf(c, re, sg * pre);
        const float nim = fmaf(c, im, sg * pim);
        re = nre; im = nim;
    };
    // RZ(th): diag(e^{-i th/2}, e^{+i th/2}); bit==0 multiply by (c - i s),
    // bit==1 multiply by (c + i s). No shuffle.
    auto RZ = [&](int pi, int m) {
        const float c = cb[pi], s = sb[pi];
        const float sg = (idx & m) ? -s : s;
        const float nre = fmaf(c, re,  sg * im);
        const float nim = fmaf(c, im, -sg * re);
        re = nre; im = nim;
    };
    // CNOT(ctrl mask cm, tgt mask tm): if ctrl bit set, take partner (tgt flipped).
    auto CNOT = [&](int cm, int tm) {
        const float pre = __shfl_xor(re, tm);
        const float pim = __shfl_xor(im, tm);
        const bool ctrl = (idx & cm) != 0;
        re = ctrl ? pre : re;
        im = ctrl ? pim : im;
    };

    const int qm0 = 8, qm1 = 4, qm2 = 2, qm3 = 1;

    // Data encoding: RX(psi[n]) on qubit n.
    RX(0, qm0); RX(1, qm1); RX(2, qm2); RX(3, qm3);

    // Variational layers.
    for (int d = 0; d < DEPTH; ++d) {
        CNOT(qm0, qm1);   // CNOT(0 -> 1)
        CNOT(qm1, qm2);   // CNOT(1 -> 2)
        CNOT(qm2, qm3);   // CNOT(2 -> 3)
        CNOT(qm3, qm0);   // CNOT(3 -> 0)
        const int base = 4 + d * 4;
        // qubit 0..3: RX then RY then RZ
        RX(base + 0, qm0); RY(40 + base + 0, qm0); RZ(80 + base + 0, qm0);
        RX(base + 1, qm1); RY(40 + base + 1, qm1); RZ(80 + base + 1, qm1);
        RX(base + 2, qm2); RY(40 + base + 2, qm2); RZ(80 + base + 2, qm2);
        RX(base + 3, qm3); RY(40 + base + 3, qm3); RZ(80 + base + 3, qm3);
    }

    const float p = fmaf(re, re, im * im);
    if (t == 0)  out[0] = p;   // K[0,0,0,0]
    if (t == 2)  out[1] = p;   // K[0,0,1,0]
    if (t == 15) out[2] = p;   // K[1,1,1,1]
}

extern "C" void kernel_launch(void* const* d_in, const int* in_sizes, int n_in,
                              void* d_out, int out_size, void* d_ws, size_t ws_size,
                              hipStream_t stream) {
    const float* psi  = (const float*)d_in[0];
    const float* ring = (const float*)d_in[1];
    const float* prx  = (const float*)d_in[2];
    const float* pry  = (const float*)d_in[3];
    const float* prz  = (const float*)d_in[4];
    float* out = (float*)d_out;
    vqc16_kernel<<<dim3(1), dim3(64), 0, stream>>>(psi, ring, prx, pry, prz, out);
}

// Round 2
// 65.164 us; speedup vs baseline: 1.0137x; 1.0137x over previous
//
#include <hip/hip_runtime.h>
#include <math.h>

// 4-qubit, depth-10 VQC — exact statevector simulation (16 complex amps),
// one amplitude per lane of a single wave. The reference's ring tensor
// network is exact (no truncation), so statevector evolution is identical.
//
// Amplitude linear index: idx = i0*8 + i1*4 + i2*2 + i3 (qubit n -> mask 8>>n).
// Outputs: |amp[0]|^2, |amp[2]|^2, |amp[15]|^2  (K[0000], K[0010], K[1111]).
//
// R1 change: libm sincosf -> native __sincosf (v_sin_f32/v_cos_f32 path).
// Kernel-side cost is already ~µs; this tests whether dur_us has any
// kernel-bound component left or is purely harness poison/restore floor.

#define DEPTH 10
#define NPAR  124   // 4 (psi) + 40 (RX) + 40 (RY) + 40 (RZ)

__global__ __launch_bounds__(64)
void vqc16_kernel(const float* __restrict__ psi,
                  const float* __restrict__ ring,   // [4][2]
                  const float* __restrict__ prx,    // [10][4]
                  const float* __restrict__ pry,
                  const float* __restrict__ prz,
                  float* __restrict__ out)          // [3]
{
    __shared__ float cb[NPAR];
    __shared__ float sb[NPAR];
    const int t = threadIdx.x;

    // Phase 1: all half-angle sincos coefficients in parallel (2 per lane).
    for (int i = t; i < NPAR; i += 64) {
        float th;
        if (i < 4)       th = psi[i];
        else if (i < 44) th = prx[i - 4];
        else if (i < 84) th = pry[i - 44];
        else             th = prz[i - 84];
        float s, c;
        __sincosf(0.5f * th, &s, &c);   // native hw sin/cos
        cb[i] = c;
        sb[i] = s;
    }
    __syncthreads();

    // Phase 2: statevector evolution, one amplitude per lane.
    // Lanes 16..63 run harmless replicas (xor masks <= 8 keep each
    // 16-lane group closed under the shuffles).
    const int idx = t & 15;
    const int b0 = (idx >> 3) & 1;
    const int b1 = (idx >> 2) & 1;
    const int b2 = (idx >> 1) & 1;
    const int b3 = idx & 1;

    // Initial product state (real): prod_n ring_init[n][bit_n]
    float re = ring[0 + b0] * ring[2 + b1] * ring[4 + b2] * ring[6 + b3];
    float im = 0.0f;

    // RX(th): [[c, -i s], [-i s, c]]
    //   new = c*self - i*s*partner -> re' = c*re + s*p_im ; im' = c*im - s*p_re
    auto RX = [&](int pi, int m) {
        const float c = cb[pi], s = sb[pi];
        const float pre = __shfl_xor(re, m);
        const float pim = __shfl_xor(im, m);
        const float nre = fmaf(c, re,  s * pim);
        const float nim = fmaf(c, im, -s * pre);
        re = nre; im = nim;
    };
    // RY(th): [[c, -s], [s, c]] (real)
    //   bit==0: new = c*self - s*partner ; bit==1: new = c*self + s*partner
    auto RY = [&](int pi, int m) {
        const float c = cb[pi], s = sb[pi];
        const float sg = (idx & m) ? s : -s;
        const float pre = __shfl_xor(re, m);
        const float pim = __shfl_xor(im, m);
        const float nre = fmaf(c, re, sg * pre);
        const float nim = fmaf(c, im, sg * pim);
        re = nre; im = nim;
    };
    // RZ(th): diag(e^{-i th/2}, e^{+i th/2}); bit==0 multiply by (c - i s),
    // bit==1 multiply by (c + i s). No shuffle.
    auto RZ = [&](int pi, int m) {
        const float c = cb[pi], s = sb[pi];
        const float sg = (idx & m) ? -s : s;
        const float nre = fmaf(c, re,  sg * im);
        const float nim = fmaf(c, im, -sg * re);
        re = nre; im = nim;
    };
    // CNOT(ctrl mask cm, tgt mask tm): if ctrl bit set, take partner (tgt flipped).
    auto CNOT = [&](int cm, int tm) {
        const float pre = __shfl_xor(re, tm);
        const float pim = __shfl_xor(im, tm);
        const bool ctrl = (idx & cm) != 0;
        re = ctrl ? pre : re;
        im = ctrl ? pim : im;
    };

    const int qm0 = 8, qm1 = 4, qm2 = 2, qm3 = 1;

    // Data encoding: RX(psi[n]) on qubit n.
    RX(0, qm0); RX(1, qm1); RX(2, qm2); RX(3, qm3);

    // Variational layers.
    for (int d = 0; d < DEPTH; ++d) {
        CNOT(qm0, qm1);   // CNOT(0 -> 1)
        CNOT(qm1, qm2);   // CNOT(1 -> 2)
        CNOT(qm2, qm3);   // CNOT(2 -> 3)
        CNOT(qm3, qm0);   // CNOT(3 -> 0)
        const int base = 4 + d * 4;
        // qubit 0..3: RX then RY then RZ
        RX(base + 0, qm0); RY(40 + base + 0, qm0); RZ(80 + base + 0, qm0);
        RX(base + 1, qm1); RY(40 + base + 1, qm1); RZ(80 + base + 1, qm1);
        RX(base + 2, qm2); RY(40 + base + 2, qm2); RZ(80 + base + 2, qm2);
        RX(base + 3, qm3); RY(40 + base + 3, qm3); RZ(80 + base + 3, qm3);
    }

    const float p = fmaf(re, re, im * im);
    if (t == 0)  out[0] = p;   // K[0,0,0,0]
    if (t == 2)  out[1] = p;   // K[0,0,1,0]
    if (t == 15) out[2] = p;   // K[1,1,1,1]
}

extern "C" void kernel_launch(void* const* d_in, const int* in_sizes, int n_in,
                              void* d_out, int out_size, void* d_ws, size_t ws_size,
                              hipStream_t stream) {
    const float* psi  = (const float*)d_in[0];
    const float* ring = (const float*)d_in[1];
    const float* prx  = (const float*)d_in[2];
    const float* pry  = (const float*)d_in[3];
    const float* prz  = (const float*)d_in[4];
    float* out = (float*)d_out;
    vqc16_kernel<<<dim3(1), dim3(64), 0, stream>>>(psi, ring, prx, pry, prz, out);
}